// Round 2
// baseline (1532.016 us; speedup 1.0000x reference)
//
#include <hip/hip_runtime.h>
#include <hip/hip_bf16.h>
#include <math.h>

#define NB 16
#define NIN 2048
#define NOUT 512
#define TT 1000
#define L_SRM 31
#define CAP 320

// ---------------- kernel 1: transpose W [512][2048] -> WT [2048][512] ----------
__global__ void k_transpose(const float* __restrict__ W, float* __restrict__ WT) {
    int idx = blockIdx.x * 256 + threadIdx.x;   // over 2048*512
    int i = idx >> 9;        // input channel
    int o = idx & 511;       // output channel
    WT[idx] = W[o * NIN + i];
}

// ---------------- kernel 2: extract active-input index lists per (n,t) --------
// one wave (64 lanes) per (n,i) row; block = 256 threads = 4 rows
__global__ void k_extract(const float* __restrict__ s,
                          int* __restrict__ cnt,
                          unsigned short* __restrict__ lists) {
    int row = blockIdx.x * 4 + (threadIdx.x >> 6);   // n*NIN + i
    int lane = threadIdx.x & 63;
    int n = row >> 11;          // NIN = 2048 = 2^11
    int i = row & (NIN - 1);
    const float* rp = s + (size_t)row * TT;
    for (int t = lane; t < TT; t += 64) {
        if (rp[t] != 0.0f) {
            int nt = n * TT + t;
            int pos = atomicAdd(&cnt[nt], 1);
            if (pos < CAP) lists[(size_t)nt * CAP + pos] = (unsigned short)i;
        }
    }
}

// ---------------- kernel 3: sparse accumulate z[n][t][o] = sum_{active i} WT[i][o]
// f64 accumulation of f32 weights: exact to ~1e-13 (order-independent in practice)
__global__ __launch_bounds__(512) void k_spmm(const int* __restrict__ cnt,
                                              const unsigned short* __restrict__ lists,
                                              const float* __restrict__ WT,
                                              double* __restrict__ z) {
    int nt = blockIdx.x;        // 0 .. NB*TT-1
    int o  = threadIdx.x;       // 512
    __shared__ unsigned short sidx[CAP];
    int c = cnt[nt];
    if (c > CAP) c = CAP;
    const unsigned short* lp = lists + (size_t)nt * CAP;
    if (threadIdx.x < c) sidx[threadIdx.x] = lp[threadIdx.x];
    __syncthreads();
    double a0 = 0., a1 = 0., a2 = 0., a3 = 0.;
    int j = 0;
    for (; j + 3 < c; j += 4) {
        a0 += (double)WT[(size_t)sidx[j]     * NOUT + o];
        a1 += (double)WT[(size_t)sidx[j + 1] * NOUT + o];
        a2 += (double)WT[(size_t)sidx[j + 2] * NOUT + o];
        a3 += (double)WT[(size_t)sidx[j + 3] * NOUT + o];
    }
    for (; j < c; ++j) a0 += (double)WT[(size_t)sidx[j] * NOUT + o];
    z[(size_t)nt * NOUT + o] = (a0 + a1) + (a2 + a3);
}

// ---------------- kernel 4: temporal conv wpsp[n][t][o] = sum_j srm[j]*z[n][t-j][o]
// block: 128 threads (one 128-o chunk); t-chunk 32, halo 30 -> 62 rows.
// LDS = 62*128*8 = 63488 B (< 64 KB).
__global__ __launch_bounds__(128) void k_conv(const double* __restrict__ z,
                                              double* __restrict__ wpsp) {
    __shared__ float srm_s[32];
    __shared__ double zs[62 * 128];
    int tid = threadIdx.x;
    if (tid < L_SRM) {
        // match np: f64 alpha samples cast to f32 (SRM_KERNEL values)
        double t = (double)tid;
        srm_s[tid] = (float)((t / 4.0) * exp(1.0 - t / 4.0));   // * TS(=1)
    }
    int tb = blockIdx.x * 32;
    int oc = blockIdx.y * 128;
    int n  = blockIdx.z;
    const double* zp = z + ((size_t)n * TT) * NOUT + oc;
    for (int r = 0; r < 62; ++r) {
        int t = tb - 30 + r;
        zs[r * 128 + tid] = (t >= 0 && t < TT) ? zp[(size_t)t * NOUT + tid] : 0.0;
    }
    __syncthreads();
    for (int tl = 0; tl < 32; ++tl) {
        int t = tb + tl;
        if (t >= TT) break;
        double acc = 0.0;
        #pragma unroll
        for (int jj = 0; jj < L_SRM; ++jj)
            acc += (double)srm_s[jj] * zs[(tl + 30 - jj) * 128 + tid];
        wpsp[((size_t)n * TT + t) * NOUT + oc + tid] = acc;
    }
}

// ---------------- kernel 5: sequential spike scan with bitmask refractory -----
// block: 64 threads (1 wave), handles one n and a 64-wide o-chunk.
// spike at time ts affects u at ts+d by REF_KERNEL[d], d=1..63 (len-64 kernel,
// REF_SHIFT = [refK[1:], 0]); 63-bit history mask reproduces exactly.
__global__ __launch_bounds__(64) void k_scan(const double* __restrict__ wpsp,
                                             float* __restrict__ out) {
    __shared__ float refTab[64];        // f32 REF_KERNEL values (as in reference)
    __shared__ double xbuf[32 * 64];    // staged wpsp chunk [t][o]
    __shared__ float obuf[64 * 33];     // output stage [o][t], padded
    int lane = threadIdx.x;
    {
        double d = (double)lane;
        refTab[lane] = (lane == 0) ? 0.0f
                     : (float)(-2.0 * 10.0 * (d / 4.0) * exp(1.0 - d / 4.0));
    }
    __syncthreads();
    int n  = blockIdx.x >> 3;
    int o0 = (blockIdx.x & 7) << 6;
    unsigned long long hist = 0ULL;     // bit b set <=> spike at t-(b+1)
    const double* wp = wpsp + ((size_t)n * TT) * NOUT + o0;
    float* op = out + ((size_t)(n * NOUT) + o0 + lane) * TT;
    for (int tb = 0; tb < TT; tb += 32) {
        int nrows = TT - tb; if (nrows > 32) nrows = 32;
        __syncthreads();
        for (int k = 0; k < nrows; ++k)
            xbuf[k * 64 + lane] = wp[(size_t)(tb + k) * NOUT + lane];
        __syncthreads();
        for (int tl = 0; tl < nrows; ++tl) {
            double x = xbuf[tl * 64 + lane];
            double R = 0.0;
            unsigned long long h = hist;
            while (h) {
                int b = __builtin_ctzll(h);
                R += (double)refTab[b + 1];
                h &= h - 1;
            }
            double u = x + R;
            bool sp = (u >= 10.0);
            hist = ((hist << 1) | (unsigned long long)sp) & 0x7FFFFFFFFFFFFFFFULL;
            obuf[lane * 33 + tl] = sp ? 1.0f : 0.0f;
        }
        __syncthreads();
        for (int k = 0; k < nrows; k += 4) {
            float4 v = make_float4(obuf[lane * 33 + k],     obuf[lane * 33 + k + 1],
                                   obuf[lane * 33 + k + 2], obuf[lane * 33 + k + 3]);
            *(float4*)(op + tb + k) = v;
        }
    }
}

extern "C" void kernel_launch(void* const* d_in, const int* in_sizes, int n_in,
                              void* d_out, int out_size, void* d_ws, size_t ws_size,
                              hipStream_t stream) {
    const float* spikeInput = (const float*)d_in[0];   // [16][2048][1000]
    const float* weight     = (const float*)d_in[1];   // [512][2048]
    float* out = (float*)d_out;                        // [16][512][1000]

    char* ws = (char*)d_ws;
    int*            cnt   = (int*)ws;                              //     64,000 B
    unsigned short* lists = (unsigned short*)(ws + 65536);         // 10,240,000 B
    float*          WT    = (float*)(ws + 10305536);               //  4,194,304 B
    double*         z     = (double*)(ws + 14499840);              // 65,536,000 B
    double*         wpsp  = (double*)(ws + 80035840);              // 65,536,000 B
    // total: 145,571,840 B

    hipMemsetAsync(cnt, 0, NB * TT * sizeof(int), stream);

    k_transpose<<<(NIN * NOUT) / 256, 256, 0, stream>>>(weight, WT);
    k_extract<<<(NB * NIN) / 4, 256, 0, stream>>>(spikeInput, cnt, lists);
    k_spmm<<<NB * TT, 512, 0, stream>>>(cnt, lists, WT, z);
    k_conv<<<dim3(32, 4, 16), 128, 0, stream>>>(z, wpsp);
    k_scan<<<NB * (NOUT / 64), 64, 0, stream>>>(wpsp, out);
}

// Round 4
// 1015.306 us; speedup vs baseline: 1.5089x; 1.5089x over previous
//
#include <hip/hip_runtime.h>
#include <hip/hip_bf16.h>
#include <math.h>

#define NB 16
#define NIN 2048
#define NOUT 512
#define TT 1000
#define L_SRM 31
#define CAP 320

// ---------------- kernel 1: transpose W [512][2048] -> WT [2048][512] ----------
__global__ void k_transpose(const float* __restrict__ W, float* __restrict__ WT) {
    int idx = blockIdx.x * 256 + threadIdx.x;   // over 2048*512
    int i = idx >> 9;        // input channel
    int o = idx & 511;       // output channel
    WT[idx] = W[o * NIN + i];
}

// ---------------- kernel 2: extract active-input index lists per (n,t) --------
// one wave (64 lanes) per (n,i) row; block = 256 threads = 4 rows
__global__ void k_extract(const float* __restrict__ s,
                          int* __restrict__ cnt,
                          unsigned short* __restrict__ lists) {
    int row = blockIdx.x * 4 + (threadIdx.x >> 6);   // n*NIN + i
    int lane = threadIdx.x & 63;
    int n = row >> 11;          // NIN = 2048 = 2^11
    int i = row & (NIN - 1);
    const float* rp = s + (size_t)row * TT;
    for (int t = lane; t < TT; t += 64) {
        if (rp[t] != 0.0f) {
            int nt = n * TT + t;
            int pos = atomicAdd(&cnt[nt], 1);
            if (pos < CAP) lists[(size_t)nt * CAP + pos] = (unsigned short)i;
        }
    }
}

// ---------------- kernel 3: sparse accumulate z[n][t][o] = sum_{active i} WT[i][o]
// f64 accumulation of f32 weights: exact to ~1e-13 (order-independent in practice)
__global__ __launch_bounds__(512) void k_spmm(const int* __restrict__ cnt,
                                              const unsigned short* __restrict__ lists,
                                              const float* __restrict__ WT,
                                              double* __restrict__ z) {
    int nt = blockIdx.x;        // 0 .. NB*TT-1
    int o  = threadIdx.x;       // 512
    __shared__ unsigned short sidx[CAP];
    int c = cnt[nt];
    if (c > CAP) c = CAP;
    const unsigned short* lp = lists + (size_t)nt * CAP;
    if (threadIdx.x < c) sidx[threadIdx.x] = lp[threadIdx.x];
    __syncthreads();
    double a0 = 0., a1 = 0., a2 = 0., a3 = 0.;
    int j = 0;
    for (; j + 3 < c; j += 4) {
        a0 += (double)WT[(size_t)sidx[j]     * NOUT + o];
        a1 += (double)WT[(size_t)sidx[j + 1] * NOUT + o];
        a2 += (double)WT[(size_t)sidx[j + 2] * NOUT + o];
        a3 += (double)WT[(size_t)sidx[j + 3] * NOUT + o];
    }
    for (; j < c; ++j) a0 += (double)WT[(size_t)sidx[j] * NOUT + o];
    z[(size_t)nt * NOUT + o] = (a0 + a1) + (a2 + a3);
}

// ---------------- kernel 4: temporal conv wpsp[n][t][o] = sum_j srm[j]*z[n][t-j][o]
// block: 128 threads (one 128-o chunk); t-chunk 32, halo 30 -> 62 rows.
// LDS = 62*128*8 = 63488 B (< 64 KB).
__global__ __launch_bounds__(128) void k_conv(const double* __restrict__ z,
                                              double* __restrict__ wpsp) {
    __shared__ float srm_s[32];
    __shared__ double zs[62 * 128];
    int tid = threadIdx.x;
    if (tid < L_SRM) {
        // match np: f64 alpha samples cast to f32 (SRM_KERNEL values)
        double t = (double)tid;
        srm_s[tid] = (float)((t / 4.0) * exp(1.0 - t / 4.0));   // * TS(=1)
    }
    int tb = blockIdx.x * 32;
    int oc = blockIdx.y * 128;
    int n  = blockIdx.z;
    const double* zp = z + ((size_t)n * TT) * NOUT + oc;
    for (int r = 0; r < 62; ++r) {
        int t = tb - 30 + r;
        zs[r * 128 + tid] = (t >= 0 && t < TT) ? zp[(size_t)t * NOUT + tid] : 0.0;
    }
    __syncthreads();
    for (int tl = 0; tl < 32; ++tl) {
        int t = tb + tl;
        if (t >= TT) break;
        double acc = 0.0;
        #pragma unroll
        for (int jj = 0; jj < L_SRM; ++jj)
            acc += (double)srm_s[jj] * zs[(tl + 30 - jj) * 128 + tid];
        wpsp[((size_t)n * TT + t) * NOUT + oc + tid] = acc;
    }
}

// ---------------- kernel 5: sequential spike scan, byte-table refractory ------
// block: 64 threads (1 wave) = one n, one 64-wide o-chunk. 1000 sequential steps.
// R(t) = sum over set history bits of f32 REF_KERNEL[d]; evaluated as 8
// independent byte-indexed f64 partial-sum lookups (no serial ctz/LDS chain).
// x staged via async global_load_lds, double-buffered (latency hidden).
__global__ __launch_bounds__(64) void k_scan(const double* __restrict__ wpsp,
                                             float* __restrict__ out) {
    __shared__ float  refTab[64];                       // f32 REF_KERNEL values
    __shared__ double Tb[8][256];                       // byte partial sums, 16 KB
    __shared__ __align__(16) double xbuf[2][32 * 64];   // staged wpsp chunks, 32 KB
    __shared__ float  obuf[64 * 33];                    // output stage [o][t], padded
    int lane = threadIdx.x;
    {
        double d = (double)lane;
        refTab[lane] = (lane == 0) ? 0.0f
                     : (float)(-20.0 * (d / 4.0) * exp(1.0 - d / 4.0));
    }
    __syncthreads();
    for (int e = lane; e < 2048; e += 64) {
        int k = e >> 8, m = e & 255;
        double s = 0.0;
        #pragma unroll
        for (int j = 0; j < 8; ++j) {
            int idx = 8 * k + j + 1;
            if (((m >> j) & 1) && idx <= 63) s += (double)refTab[idx];
        }
        Tb[k][m] = s;
    }

    int n  = blockIdx.x >> 3;
    int o0 = (blockIdx.x & 7) << 6;
    const double* wp = wpsp + ((size_t)n * TT) * NOUT + o0;
    float* op = out + ((size_t)(n * NOUT) + o0 + lane) * TT;

    // stage nrows rows (64 f64 each) of wp starting at tb into xbuf[buf]:
    // per issue 2 rows: lanes 0-31 row r cols 0..63 (2 f64/lane), lanes 32-63 row r+1
    int halfSel = lane >> 5;
    int colSel  = (lane & 31) * 2;
    #define STAGE(buf, tb, nrows)                                                  \
        for (int p = 0; p < (nrows) / 2; ++p) {                                    \
            const double* src = wp + (size_t)((tb) + 2 * p + halfSel) * NOUT + colSel; \
            __builtin_amdgcn_global_load_lds(                                      \
                (const __attribute__((address_space(1))) void*)src,                \
                (__attribute__((address_space(3))) void*)(&xbuf[buf][p * 128]),    \
                16, 0, 0);                                                         \
        }

    unsigned long long hist = 0ULL;     // bit b set <=> spike at t-(b+1)
    int buf = 0;
    STAGE(0, 0, 32);
    asm volatile("s_waitcnt vmcnt(0)" ::: "memory");
    __syncthreads();

    for (int tb = 0; tb < TT; tb += 32) {
        int nrows = TT - tb; if (nrows > 32) nrows = 32;
        int nnext = TT - (tb + 32); if (nnext > 32) nnext = 32;
        if (nnext > 0) { STAGE(buf ^ 1, tb + 32, nnext); }
        for (int tl = 0; tl < nrows; ++tl) {
            double x = xbuf[buf][tl * 64 + lane];
            unsigned long long h = hist;
            double R = (Tb[0][(unsigned)( h        & 255)] + Tb[1][(unsigned)((h >>  8) & 255)])
                     + (Tb[2][(unsigned)((h >> 16) & 255)] + Tb[3][(unsigned)((h >> 24) & 255)])
                     + (Tb[4][(unsigned)((h >> 32) & 255)] + Tb[5][(unsigned)((h >> 40) & 255)])
                     + (Tb[6][(unsigned)((h >> 48) & 255)] + Tb[7][(unsigned)((h >> 56) & 255)]);
            double u = x + R;
            bool sp = (u >= 10.0);
            hist = ((hist << 1) | (unsigned long long)sp) & 0x7FFFFFFFFFFFFFFFULL;
            obuf[lane * 33 + tl] = sp ? 1.0f : 0.0f;
        }
        for (int k = 0; k + 3 < nrows; k += 4) {
            float4 v = make_float4(obuf[lane * 33 + k],     obuf[lane * 33 + k + 1],
                                   obuf[lane * 33 + k + 2], obuf[lane * 33 + k + 3]);
            *(float4*)(op + tb + k) = v;
        }
        asm volatile("s_waitcnt vmcnt(0)" ::: "memory");
        __syncthreads();
        buf ^= 1;
    }
    #undef STAGE
}

extern "C" void kernel_launch(void* const* d_in, const int* in_sizes, int n_in,
                              void* d_out, int out_size, void* d_ws, size_t ws_size,
                              hipStream_t stream) {
    const float* spikeInput = (const float*)d_in[0];   // [16][2048][1000]
    const float* weight     = (const float*)d_in[1];   // [512][2048]
    float* out = (float*)d_out;                        // [16][512][1000]

    char* ws = (char*)d_ws;
    int*            cnt   = (int*)ws;                              //     64,000 B
    unsigned short* lists = (unsigned short*)(ws + 65536);         // 10,240,000 B
    float*          WT    = (float*)(ws + 10305536);               //  4,194,304 B
    double*         z     = (double*)(ws + 14499840);              // 65,536,000 B
    double*         wpsp  = (double*)(ws + 80035840);              // 65,536,000 B
    // total: 145,571,840 B

    hipMemsetAsync(cnt, 0, NB * TT * sizeof(int), stream);

    k_transpose<<<(NIN * NOUT) / 256, 256, 0, stream>>>(weight, WT);
    k_extract<<<(NB * NIN) / 4, 256, 0, stream>>>(spikeInput, cnt, lists);
    k_spmm<<<NB * TT, 512, 0, stream>>>(cnt, lists, WT, z);
    k_conv<<<dim3(32, 4, 16), 128, 0, stream>>>(z, wpsp);
    k_scan<<<NB * (NOUT / 64), 64, 0, stream>>>(wpsp, out);
}

// Round 5
// 753.985 us; speedup vs baseline: 2.0319x; 1.3466x over previous
//
#include <hip/hip_runtime.h>
#include <hip/hip_bf16.h>
#include <math.h>

#define NB 16
#define NIN 2048
#define NOUT 512
#define TT 1000
#define L_SRM 31
#define CAP2 768

// ---------------- kernel 1: transpose W [512][2048] -> WT [2048][512] ----------
__global__ void k_transpose(const float* __restrict__ W, float* __restrict__ WT) {
    int idx = blockIdx.x * 256 + threadIdx.x;   // over 2048*512
    int i = idx >> 9;        // input channel
    int o = idx & 511;       // output channel
    WT[idx] = W[o * NIN + i];
}

// ---------------- kernel 2: ballot-transpose spike extract --------------------
// block 256 thr = 4 waves. Tile: 64 inputs x 64 timesteps. No atomics.
// out: bits[n][t][ic] (u64), bit b of word ic <=> input i = ic*64+b active at t.
__global__ __launch_bounds__(256) void k_extract(const float* __restrict__ s,
                                                 unsigned long long* __restrict__ bits) {
    __shared__ float tile[64][65];          // padded: column reads conflict-free
    int tc = blockIdx.x;                    // t-chunk (16)
    int ic = blockIdx.y;                    // i-chunk (32)
    int n  = blockIdx.z;                    // batch (16)
    int t0 = tc * 64, i0 = ic * 64;
    int tid = threadIdx.x;
    int r   = tid >> 2;                     // tile row (input)
    int cq  = tid & 3;                      // col quarter
    const float* rp = s + ((size_t)(n * NIN + i0 + r)) * TT + t0;
    #pragma unroll
    for (int q = 0; q < 4; ++q) {
        int col = cq * 16 + q * 4;
        float4 v = make_float4(0.f, 0.f, 0.f, 0.f);
        if (t0 + col + 3 < TT) v = *(const float4*)(rp + col);
        tile[r][col]     = v.x;
        tile[r][col + 1] = v.y;
        tile[r][col + 2] = v.z;
        tile[r][col + 3] = v.w;
    }
    __syncthreads();
    int lane = tid & 63;
    int w    = tid >> 6;
    #pragma unroll
    for (int k = 0; k < 16; ++k) {
        int tl = w * 16 + k;
        if (t0 + tl >= TT) break;
        float val = tile[lane][tl];
        unsigned long long m = __ballot(val != 0.0f);
        if (lane == 0)
            bits[((size_t)n * TT + t0 + tl) * 32 + ic] = m;
    }
}

// ---------------- kernel 3: sparse accumulate z[n][t][o] = sum_{active i} WT[i][o]
// active list built in-block from the bitmask; f64 accumulation (exact ~1e-13).
// z stored nontemporal so the write stream doesn't evict WT from L2.
__global__ __launch_bounds__(512) void k_spmm(const unsigned long long* __restrict__ bits,
                                              const float* __restrict__ WT,
                                              double* __restrict__ z) {
    int nt = blockIdx.x;        // 0 .. NB*TT-1
    int o  = threadIdx.x;       // 512
    __shared__ unsigned short sidx[CAP2];
    __shared__ int s_cnt;
    int tid = threadIdx.x;
    if (tid < 64) {             // wave 0 compacts 32 words -> index list
        unsigned long long w = (tid < 32) ? bits[(size_t)nt * 32 + tid] : 0ULL;
        int pc  = __popcll(w);
        int pre = pc;
        #pragma unroll
        for (int d = 1; d < 32; d <<= 1) {
            int x = __shfl_up(pre, d, 64);
            if (tid >= d) pre += x;
        }
        pre -= pc;              // exclusive prefix
        if (tid == 31) s_cnt = pre + pc;
        int base = tid * 64;
        while (w) {
            int b = __builtin_ctzll(w);
            if (pre < CAP2) sidx[pre] = (unsigned short)(base + b);
            ++pre;
            w &= w - 1;
        }
    }
    __syncthreads();
    int c = s_cnt;
    if (c > CAP2) c = CAP2;
    double a0 = 0., a1 = 0., a2 = 0., a3 = 0.;
    int j = 0;
    for (; j + 7 < c; j += 8) {
        float w0 = WT[(size_t)sidx[j]     * NOUT + o];
        float w1 = WT[(size_t)sidx[j + 1] * NOUT + o];
        float w2 = WT[(size_t)sidx[j + 2] * NOUT + o];
        float w3 = WT[(size_t)sidx[j + 3] * NOUT + o];
        float w4 = WT[(size_t)sidx[j + 4] * NOUT + o];
        float w5 = WT[(size_t)sidx[j + 5] * NOUT + o];
        float w6 = WT[(size_t)sidx[j + 6] * NOUT + o];
        float w7 = WT[(size_t)sidx[j + 7] * NOUT + o];
        a0 += (double)w0; a1 += (double)w1; a2 += (double)w2; a3 += (double)w3;
        a0 += (double)w4; a1 += (double)w5; a2 += (double)w6; a3 += (double)w7;
    }
    for (; j < c; ++j) a0 += (double)WT[(size_t)sidx[j] * NOUT + o];
    __builtin_nontemporal_store((a0 + a1) + (a2 + a3), &z[(size_t)nt * NOUT + o]);
}

// ---------------- kernel 4: temporal conv wpsp[n][t][o] = sum_j srm[j]*z[n][t-j][o]
// block: 128 threads (one 128-o chunk); t-chunk 32, halo 30 -> 62 rows.
// LDS = 62*128*8 = 63488 B (< 64 KB).
__global__ __launch_bounds__(128) void k_conv(const double* __restrict__ z,
                                              double* __restrict__ wpsp) {
    __shared__ float srm_s[32];
    __shared__ double zs[62 * 128];
    int tid = threadIdx.x;
    if (tid < L_SRM) {
        // match np: f64 alpha samples cast to f32 (SRM_KERNEL values)
        double t = (double)tid;
        srm_s[tid] = (float)((t / 4.0) * exp(1.0 - t / 4.0));   // * TS(=1)
    }
    int tb = blockIdx.x * 32;
    int oc = blockIdx.y * 128;
    int n  = blockIdx.z;
    const double* zp = z + ((size_t)n * TT) * NOUT + oc;
    for (int r = 0; r < 62; ++r) {
        int t = tb - 30 + r;
        zs[r * 128 + tid] = (t >= 0 && t < TT) ? zp[(size_t)t * NOUT + tid] : 0.0;
    }
    __syncthreads();
    for (int tl = 0; tl < 32; ++tl) {
        int t = tb + tl;
        if (t >= TT) break;
        double acc = 0.0;
        #pragma unroll
        for (int jj = 0; jj < L_SRM; ++jj)
            acc += (double)srm_s[jj] * zs[(tl + 30 - jj) * 128 + tid];
        wpsp[((size_t)n * TT + t) * NOUT + oc + tid] = acc;
    }
}

// ---------------- kernel 5: sequential spike scan, byte-table refractory ------
// block: 64 threads (1 wave) = one n, one 64-wide o-chunk. 1000 sequential steps.
// R(t) via 8 independent byte-indexed f64 partial-sum lookups (no serial chain).
// x staged via async global_load_lds, double-buffered (latency hidden).
__global__ __launch_bounds__(64) void k_scan(const double* __restrict__ wpsp,
                                             float* __restrict__ out) {
    __shared__ float  refTab[64];                       // f32 REF_KERNEL values
    __shared__ double Tb[8][256];                       // byte partial sums, 16 KB
    __shared__ __align__(16) double xbuf[2][32 * 64];   // staged wpsp chunks, 32 KB
    __shared__ float  obuf[64 * 33];                    // output stage [o][t], padded
    int lane = threadIdx.x;
    {
        double d = (double)lane;
        refTab[lane] = (lane == 0) ? 0.0f
                     : (float)(-20.0 * (d / 4.0) * exp(1.0 - d / 4.0));
    }
    __syncthreads();
    for (int e = lane; e < 2048; e += 64) {
        int k = e >> 8, m = e & 255;
        double s = 0.0;
        #pragma unroll
        for (int j = 0; j < 8; ++j) {
            int idx = 8 * k + j + 1;
            if (((m >> j) & 1) && idx <= 63) s += (double)refTab[idx];
        }
        Tb[k][m] = s;
    }

    int n  = blockIdx.x >> 3;
    int o0 = (blockIdx.x & 7) << 6;
    const double* wp = wpsp + ((size_t)n * TT) * NOUT + o0;
    float* op = out + ((size_t)(n * NOUT) + o0 + lane) * TT;

    // stage nrows rows (64 f64 each) of wp starting at tb into xbuf[buf]:
    // per issue 2 rows: lanes 0-31 row r cols 0..63 (2 f64/lane), lanes 32-63 row r+1
    int halfSel = lane >> 5;
    int colSel  = (lane & 31) * 2;
    #define STAGE(buf, tb, nrows)                                                  \
        for (int p = 0; p < (nrows) / 2; ++p) {                                    \
            const double* src = wp + (size_t)((tb) + 2 * p + halfSel) * NOUT + colSel; \
            __builtin_amdgcn_global_load_lds(                                      \
                (const __attribute__((address_space(1))) void*)src,                \
                (__attribute__((address_space(3))) void*)(&xbuf[buf][p * 128]),    \
                16, 0, 0);                                                         \
        }

    unsigned long long hist = 0ULL;     // bit b set <=> spike at t-(b+1)
    int buf = 0;
    STAGE(0, 0, 32);
    asm volatile("s_waitcnt vmcnt(0)" ::: "memory");
    __syncthreads();

    for (int tb = 0; tb < TT; tb += 32) {
        int nrows = TT - tb; if (nrows > 32) nrows = 32;
        int nnext = TT - (tb + 32); if (nnext > 32) nnext = 32;
        if (nnext > 0) { STAGE(buf ^ 1, tb + 32, nnext); }
        for (int tl = 0; tl < nrows; ++tl) {
            double x = xbuf[buf][tl * 64 + lane];
            unsigned long long h = hist;
            double R = (Tb[0][(unsigned)( h        & 255)] + Tb[1][(unsigned)((h >>  8) & 255)])
                     + (Tb[2][(unsigned)((h >> 16) & 255)] + Tb[3][(unsigned)((h >> 24) & 255)])
                     + (Tb[4][(unsigned)((h >> 32) & 255)] + Tb[5][(unsigned)((h >> 40) & 255)])
                     + (Tb[6][(unsigned)((h >> 48) & 255)] + Tb[7][(unsigned)((h >> 56) & 255)]);
            double u = x + R;
            bool sp = (u >= 10.0);
            hist = ((hist << 1) | (unsigned long long)sp) & 0x7FFFFFFFFFFFFFFFULL;
            obuf[lane * 33 + tl] = sp ? 1.0f : 0.0f;
        }
        for (int k = 0; k + 3 < nrows; k += 4) {
            float4 v = make_float4(obuf[lane * 33 + k],     obuf[lane * 33 + k + 1],
                                   obuf[lane * 33 + k + 2], obuf[lane * 33 + k + 3]);
            *(float4*)(op + tb + k) = v;
        }
        asm volatile("s_waitcnt vmcnt(0)" ::: "memory");
        __syncthreads();
        buf ^= 1;
    }
    #undef STAGE
}

extern "C" void kernel_launch(void* const* d_in, const int* in_sizes, int n_in,
                              void* d_out, int out_size, void* d_ws, size_t ws_size,
                              hipStream_t stream) {
    const float* spikeInput = (const float*)d_in[0];   // [16][2048][1000]
    const float* weight     = (const float*)d_in[1];   // [512][2048]
    float* out = (float*)d_out;                        // [16][512][1000]

    char* ws = (char*)d_ws;
    unsigned long long* bits = (unsigned long long*)ws;            //  4,096,000 B
    float*              WT   = (float*)(ws + 4194304);             //  4,194,304 B
    double*             z    = (double*)(ws + 8388608);            // 65,536,000 B
    double*             wpsp = (double*)(ws + 73924608);           // 65,536,000 B
    // total: 139,460,608 B

    k_transpose<<<(NIN * NOUT) / 256, 256, 0, stream>>>(weight, WT);
    k_extract<<<dim3(16, 32, 16), 256, 0, stream>>>(spikeInput, bits);
    k_spmm<<<NB * TT, 512, 0, stream>>>(bits, WT, z);
    k_conv<<<dim3(32, 4, 16), 128, 0, stream>>>(z, wpsp);
    k_scan<<<NB * (NOUT / 64), 64, 0, stream>>>(wpsp, out);
}